// Round 18
// baseline (104.776 us; speedup 1.0000x reference)
//
#include <hip/hip_runtime.h>
#include <math.h>
#include <stdint.h>

#define NM 8          // nmul
#define NPAR 12
#define GPB 16        // g's per block -> 128 chains, 2 per lane
#define KS 16         // timesteps per pipeline round
#define ROWDW (GPB*3) // 48 dwords = 192B per forcing row
#define NLL 3         // 1KB global_load_lds ops per chunk (KS*192/1024)

typedef __attribute__((address_space(1))) const void gv_t;
typedef __attribute__((address_space(3))) void lv_t;
typedef float v2f __attribute__((ext_vector_type(2)));
typedef float v4f __attribute__((ext_vector_type(4)));

// Block = 128 threads = 2 waves, 128 chains (16 g x 8 m), 2 chains/lane.
// Wave 0 (producer): staging + snow x2 -> ring (ds_write_b128 per lane-step).
// Wave 1 (consumer): soil + response x2 -> out. One round behind.
// All pipelined DS ops are volatile asm. WAITs do waitcnt + SYNCHRONOUS v_mov
// extraction into early-clobber regs (R16-proven; R17's "+v" pass-through let
// in-flight ds_reads clobber live values -> absmax 7.4). Ring-write data lives
// in persistent double-buffered regs so its registers outlive the lgkm drain.
__global__ __launch_bounds__(128, 1) void hbv_kernel(
    const float* __restrict__ x,      // [T, G, 3]  (prcp, tmean, pet)
    const float* __restrict__ praw,   // [1, G, 12, NM] in [0,1)
    float* __restrict__ out,          // [T, G, NM]
    int G, int T)
{
    __shared__ float fbuf[2][(KS + 2) * ROWDW];  // forcing, +2 pad rows
    __shared__ v4f   ring[2][KS + 2][64];        // (rtA,E,rtB,E), +2 pad

    const int wid  = threadIdx.x >> 6;      // 0 producer, 1 consumer
    const int lane = threadIdx.x & 63;
    const int b    = blockIdx.x;
    const int gl   = lane >> 2;             // g within block, 0..15
    const int m0   = (lane & 3) << 1;       // 0,2,4,6
    const int g    = (b << 4) + gl;         // G % 16 == 0 (4000 -> 250 blocks)

    // Parameter bounds: BETA, FC, K0, K1, K2, LP, PERC, UZL, TT, CFMAX, CFR, CWH
    const float lb[NPAR] = {1.0f, 50.0f, 0.05f, 0.01f, 0.001f, 0.2f, 0.0f, 0.0f, -2.5f, 0.5f, 0.0f, 0.0f};
    const float ub[NPAR] = {6.0f, 1000.0f, 0.9f, 0.5f, 0.2f, 1.0f, 10.0f, 100.0f, 2.5f, 10.0f, 0.1f, 0.2f};

    float pA[NPAR], pB[NPAR];
    const float* pr = praw + (size_t)g * (NPAR * NM) + m0;
    #pragma unroll
    for (int i = 0; i < NPAR; ++i) {
        const float s = ub[i] - lb[i];
        pA[i] = pr[i * NM]     * s + lb[i];  // adjacent dwords -> dwordx2
        pB[i] = pr[i * NM + 1] * s + lb[i];
    }

    const int NBLK = (T + KS - 1) / KS;     // 46 rounds (T=730; last cnt=10, even)

    // issue one forcing-row read (P,T via read2; E single) -- 2 DS ops
    #define ISSUE_F(fa_, pt_, e_)                                              \
        asm volatile("ds_read2_b32 %0, %2 offset0:0 offset1:1\n\t"             \
                     "ds_read_b32 %1, %2 offset:8"                             \
                     : "=v"(pt_), "=v"(e_) : "v"(fa_));
    // waitcnt + synchronous extraction to DISJOINT regs (early-clobber):
    // after this asm, P_/T_/E_ are stable even when pt_/e_ are re-issued.
    #define WAIT_F(pt_, e_, P_, T_, E_)                                        \
        asm volatile("s_waitcnt lgkmcnt(2)\n\t"                                \
                     "v_mov_b32 %0, %3\n\t"                                    \
                     "v_mov_b32 %1, %4\n\t"                                    \
                     "v_mov_b32 %2, %5"                                        \
                     : "=&v"(P_), "=&v"(T_), "=&v"(E_)                         \
                     : "v"(pt_.x), "v"(pt_.y), "v"(e_));
    #define WRITE_R(wa_, w_)                                                   \
        asm volatile("ds_write_b128 %0, %1" :: "v"(wa_), "v"(w_));
    #define ISSUE_C(ca_, rel_)                                                 \
        asm volatile("ds_read_b128 %0, %1" : "=v"(rel_) : "v"(ca_));
    #define WAIT_C(rel_, rtA_, EA_, rtB_, EB_)                                 \
        asm volatile("s_waitcnt lgkmcnt(1)\n\t"                                \
                     "v_mov_b32 %0, %4\n\t"                                    \
                     "v_mov_b32 %1, %5\n\t"                                    \
                     "v_mov_b32 %2, %6\n\t"                                    \
                     "v_mov_b32 %3, %7"                                        \
                     : "=&v"(rtA_), "=&v"(EA_), "=&v"(rtB_), "=&v"(EB_)        \
                     : "v"(rel_.x), "v"(rel_.y), "v"(rel_.z), "v"(rel_.w));

    if (wid == 0) {
        // ------------------------- PRODUCER (snow x2) -------------------------
        const float TTa = pA[8],  TTb = pB[8];
        const float CFa = pA[9],  CFb = pB[9];
        const float nCMa = -(CFa * TTa),          nCMb = -(CFb * TTb);
        const float nCRa = -(pA[10] * CFa),       nCRb = -(pB[10] * CFb);
        const float CRTa = (pA[10] * CFa) * TTa,  CRTb = (pB[10] * CFb) * TTb;
        const float CWa  = pA[11],                CWb  = pB[11];

        float SPa = 0.001f, MWa = 0.001f, SPb = 0.001f, MWb = 0.001f;

        // forcing chunk-copy geometry (16B-aligned: row 192B, gbase = 192*b)
        const char* xb = (const char*)x;
        const uint32_t xstep  = (uint32_t)G * 12u;
        const uint32_t gbase  = (uint32_t)(b << 4) * 12u;
        const uint32_t lin    = (uint32_t)lane * 16u;
        const uint32_t r0     = lin / 192u;
        const uint32_t c0     = lin % 192u;
        const uint32_t rowmax = (uint32_t)(T - 1);

        #define ISSUE_CHUNK(cs_, nb_)                                          \
        {                                                                      \
            uint32_t row_ = (uint32_t)(cs_) + r0;                              \
            uint32_t col_ = c0;                                                \
            _Pragma("unroll")                                                  \
            for (int i_ = 0; i_ < NLL; ++i_) {                                 \
                const uint32_t rg_ = row_ < rowmax ? row_ : rowmax;            \
                const uint32_t go_ = rg_ * xstep + gbase + col_;               \
                __builtin_amdgcn_global_load_lds((gv_t*)(xb + go_),            \
                    (lv_t*)&fbuf[nb_][i_ * 256], 16, 0, 0);                    \
                /* +1024B = 5 rows + 64B within the 192B-row raster */         \
                row_ += 5u + (col_ >= 128u ? 1u : 0u);                         \
                col_  = (col_ >= 128u) ? (col_ - 128u) : (col_ + 64u);         \
            }                                                                  \
        }

        ISSUE_CHUNK(0, 0)

        for (int r = 0; r <= NBLK; ++r) {
            if (r < NBLK) {
                if (r + 1 < NBLK) {
                    ISSUE_CHUNK((r + 1) * KS, (r + 1) & 1)
                    asm volatile("s_waitcnt vmcnt(3)" ::: "memory");
                } else {
                    asm volatile("s_waitcnt vmcnt(0)" ::: "memory");
                }
                const int cnt = (T - r * KS < KS) ? (T - r * KS) : KS;  // 16 or 10: even
                uint32_t fa = (uint32_t)(uintptr_t)&fbuf[r & 1][gl * 3];
                uint32_t wa = (uint32_t)(uintptr_t)&ring[r & 1][0][lane];

                v2f pt0, pt1; float e0, e1;
                v4f w0, w1;                          // persistent write-data regs:
                ISSUE_F(fa, pt0, e0) fa += 192;      // reassigned only after the
                ISSUE_F(fa, pt1, e1) fa += 192;      // WAIT that drains their write

                #define PROD_STEP(PT_, E_, W_)                                 \
                {                                                              \
                    float P, Tt, E;                                            \
                    WAIT_F(PT_, E_, P, Tt, E)                                  \
                    const float rnA = (Tt >= TTa) ? P : 0.0f;                  \
                    const float rnB = (Tt >= TTb) ? P : 0.0f;                  \
                    const float mcA = fmaxf(fmaf(CFa, Tt, nCMa), 0.0f);        \
                    const float mcB = fmaxf(fmaf(CFb, Tt, nCMb), 0.0f);        \
                    const float rcA = fmaxf(fmaf(nCRa, Tt, CRTa), 0.0f);       \
                    const float rcB = fmaxf(fmaf(nCRb, Tt, CRTb), 0.0f);       \
                    SPa += P - rnA;                 SPb += P - rnB;            \
                    const float mA = fminf(mcA, SPa);                          \
                    const float mB = fminf(mcB, SPb);                          \
                    MWa += mA; SPa -= mA;           MWb += mB; SPb -= mB;      \
                    const float rA = fminf(rcA, MWa);                          \
                    const float rB = fminf(rcB, MWb);                          \
                    SPa += rA; MWa -= rA;           SPb += rB; MWb -= rB;      \
                    const float cA = CWa * SPa;     const float cB = CWb * SPb;\
                    const float tA = fmaxf(MWa - cA, 0.0f);                    \
                    const float tB = fmaxf(MWb - cB, 0.0f);                    \
                    MWa = fminf(MWa, cA);           MWb = fminf(MWb, cB);      \
                    W_.x = rnA + tA; W_.y = E; W_.z = rnB + tB; W_.w = E;      \
                    WRITE_R(wa, W_)                                            \
                    wa += 1024;                                                \
                    ISSUE_F(fa, PT_, E_)            /* row tt+2 (pad safe) */  \
                    fa += 192;                                                 \
                }

                for (int tt = 0; tt < cnt; tt += 2) {
                    PROD_STEP(pt0, e0, w0)
                    PROD_STEP(pt1, e1, w1)
                }
                #undef PROD_STEP
            }
            // drain asm ds_writes (and dead prefetches) before the barrier:
            // consumer must see this round's ring data.
            asm volatile("s_waitcnt lgkmcnt(0)" ::: "memory");
            __syncthreads();
        }
        #undef ISSUE_CHUNK
    } else {
        // ------------------ CONSUMER (soil + response x2) ------------------
        const float BEa = pA[0], BEb = pB[0];
        const float FCa = pA[1], FCb = pB[1];
        const float iLa = 1.0f / (pA[5] * FCa),  iLb = 1.0f / (pB[5] * FCb);
        const float nBa = -BEa * __builtin_amdgcn_logf(FCa);   // -BETA*log2(FC)
        const float nBb = -BEb * __builtin_amdgcn_logf(FCb);
        const float OK0a = 1.0f - pA[2],  OK0b = 1.0f - pB[2];
        const float KUa  = pA[2] * pA[7], KUb  = pB[2] * pB[7];
        const float OK1a = 1.0f - pA[3],  OK1b = 1.0f - pB[3];
        const float PCa  = pA[6],         PCb  = pB[6];
        const float K2a  = pA[4],         K2b  = pB[4];
        const float OK2a = 1.0f - K2a,    OK2b = 1.0f - K2b;

        float SMa = 0.001f, SUa = 0.001f, SLa = 0.001f;
        float SMb = 0.001f, SUb = 0.001f, SLb = 0.001f;

        char* ob = (char*)out;
        uint32_t ooff = (uint32_t)((b << 7) + (lane << 1)) * 4u;  // g*NM + m0
        const uint32_t ostep = (uint32_t)(G * NM) * 4u;

        for (int r = 0; r <= NBLK; ++r) {
            if (r >= 1) {
                const int base = (r - 1) * KS;
                const int cnt  = (T - base < KS) ? (T - base) : KS;   // even
                uint32_t ca = (uint32_t)(uintptr_t)&ring[(r - 1) & 1][0][lane];

                v4f rel0, rel1;
                ISSUE_C(ca, rel0) ca += 1024;        // row 0 (64 x 16B)
                ISSUE_C(ca, rel1) ca += 1024;        // row 1

                #define CONS_STEP(REL_)                                        \
                {                                                              \
                    float rtA, EA, rtB, EB;                                    \
                    WAIT_C(REL_, rtA, EA, rtB, EB)                             \
                    ISSUE_C(ca, REL_) ca += 1024;    /* row tt+2 (pad safe) */ \
                    /* soil A|B interleaved */                                 \
                    const float lgA = __builtin_amdgcn_logf(SMa);              \
                    const float lgB = __builtin_amdgcn_logf(SMb);              \
                    const float blA = fminf(fmaf(BEa, lgA, nBa), 0.0f);        \
                    const float blB = fminf(fmaf(BEb, lgB, nBb), 0.0f);        \
                    const float swA = __builtin_amdgcn_exp2f(blA);             \
                    const float swB = __builtin_amdgcn_exp2f(blB);             \
                    const float rgA = rtA * swA;     const float rgB = rtB * swB; \
                    const float S1A = SMa + rtA - rgA;                         \
                    const float S1B = SMb + rtB - rgB;                         \
                    const float exA = fmaxf(S1A - FCa, 0.0f);                  \
                    const float exB = fmaxf(S1B - FCb, 0.0f);                  \
                    const float S2A = fminf(S1A, FCa);                         \
                    const float S2B = fminf(S1B, FCb);                         \
                    const float oPA = fmaf(-EA, iLa, 1.0f);                    \
                    const float oPB = fmaf(-EB, iLb, 1.0f);                    \
                    SMa = fmaxf(fmaxf(S2A * oPA, S2A - EA), 1e-5f);            \
                    SMb = fmaxf(fmaxf(S2B * oPB, S2B - EB), 1e-5f);            \
                    /* response A|B (Q0+Q1 == s2 - s4) */                      \
                    SUa = SUa + rgA + exA;           SUb = SUb + rgB + exB;    \
                    const float pcA = fminf(SUa, PCa);                         \
                    const float pcB = fminf(SUb, PCb);                         \
                    const float s2A = fmaxf(SUa - PCa, 0.0f);                  \
                    const float s2B = fmaxf(SUb - PCb, 0.0f);                  \
                    const float s3A = fminf(s2A, fmaf(OK0a, s2A, KUa));        \
                    const float s3B = fminf(s2B, fmaf(OK0b, s2B, KUb));        \
                    const float s4A = s3A * OK1a;    const float s4B = s3B * OK1b; \
                    SUa = s4A;                       SUb = s4B;                \
                    const float slA = SLa + pcA;     const float slB = SLb + pcB; \
                    const float q2A = K2a * slA;     const float q2B = K2b * slB; \
                    SLa = slA * OK2a;                SLb = slB * OK2b;         \
                    v2f q; q.x = (s2A - s4A) + q2A;  q.y = (s2B - s4B) + q2B;  \
                    *(v2f*)(ob + ooff) = q;          /* dwordx2, coalesced */  \
                    ooff += ostep;                                             \
                }

                for (int tt = 0; tt < cnt; tt += 2) {
                    CONS_STEP(rel0)
                    CONS_STEP(rel1)
                }
                #undef CONS_STEP
            }
            __syncthreads();
        }
    }
    #undef ISSUE_F
    #undef WAIT_F
    #undef WRITE_R
    #undef ISSUE_C
    #undef WAIT_C
}

extern "C" void kernel_launch(void* const* d_in, const int* in_sizes, int n_in,
                              void* d_out, int out_size, void* d_ws, size_t ws_size,
                              hipStream_t stream) {
    const float* x    = (const float*)d_in[0];   // [T, G, 3]
    const float* praw = (const float*)d_in[1];   // [1, G, 12, 8]
    float* out = (float*)d_out;                  // [T, G, 8]

    const int G = in_sizes[1] / (NPAR * NM);     // 4000
    const int T = in_sizes[0] / (3 * G);         // 730

    const int grid = G / GPB;                    // 250 blocks x 2 waves
    hbv_kernel<<<grid, 128, 0, stream>>>(x, praw, out, G, T);
}

// Round 19
// 70.887 us; speedup vs baseline: 1.4781x; 1.4781x over previous
//
#include <hip/hip_runtime.h>
#include <math.h>
#include <stdint.h>

#define NM 8          // nmul
#define NPAR 12
#define KS 32         // timesteps per pipeline round (= forcing chunk)
#define NLL 3         // 1KB global_load_lds ops per forcing chunk (KS*96/1024)

typedef __attribute__((address_space(1))) const void gv_t;
typedef __attribute__((address_space(3))) void lv_t;
typedef float v2f __attribute__((ext_vector_type(2)));

// Block = 128 threads = 2 waves, 64 chains (8 g x 8 m).
// Wave 0 (producer): staging + snow routine -> relays (rt, E) through LDS ring.
// Wave 1 (consumer): soil + response -> stores Q. One round behind.
// Per-step LDS reads are issued 2 steps ahead via volatile asm, with a combined
// waitcnt+extract asm (data-dependence ordering, NO sched fences) so the
// ~120-cyc ds_read latency leaves the per-step serial path.
__global__ __launch_bounds__(128, 1) void hbv_kernel(
    const float* __restrict__ x,      // [T, G, 3]  (prcp, tmean, pet)
    const float* __restrict__ praw,   // [1, G, 12, NM] in [0,1)
    float* __restrict__ out,          // [T, G, NM]
    int G, int T)
{
    __shared__ float  fbuf[2][(KS + 2) * 24];   // +2 pad rows for t+2 prefetch
    __shared__ float2 ring[2][KS + 2][64];      // +2 pad rows

    const int wid  = threadIdx.x >> 6;      // 0 producer, 1 consumer
    const int lane = threadIdx.x & 63;
    const int b    = blockIdx.x;
    const int g0   = b << 3;
    const int gl   = lane >> 3;             // g within block
    const int m    = lane & 7;
    const int g    = g0 + gl;

    // Parameter bounds: BETA, FC, K0, K1, K2, LP, PERC, UZL, TT, CFMAX, CFR, CWH
    const float lb[NPAR] = {1.0f, 50.0f, 0.05f, 0.01f, 0.001f, 0.2f, 0.0f, 0.0f, -2.5f, 0.5f, 0.0f, 0.0f};
    const float ub[NPAR] = {6.0f, 1000.0f, 0.9f, 0.5f, 0.2f, 1.0f, 10.0f, 100.0f, 2.5f, 10.0f, 0.1f, 0.2f};

    float p[NPAR];
    const float* pr = praw + (size_t)g * (NPAR * NM) + m;
    #pragma unroll
    for (int i = 0; i < NPAR; ++i) p[i] = pr[i * NM] * (ub[i] - lb[i]) + lb[i];

    const int NBLK = (T + KS - 1) / KS;     // 23 rounds of work

    // issue one forcing-row read (P,T via read2; E single) -- 2 DS ops
    #define ISSUE_F(fa_, pt_, e_)                                              \
        asm volatile("ds_read2_b32 %0, %2 offset0:0 offset1:1\n\t"             \
                     "ds_read_b32 %1, %2 offset:8"                             \
                     : "=v"(pt_), "=v"(e_) : "v"(fa_));
    // wait until this slot's reads done (<=2 newer DS ops allowed in flight),
    // then extract; "+v"-style data deps order all consumers after the wait.
    #define WAIT_F(pt_, e_, P_, T_, E_)                                        \
        asm volatile("s_waitcnt lgkmcnt(2)\n\t"                                \
                     "v_mov_b32 %0, %3\n\t"                                    \
                     "v_mov_b32 %1, %4\n\t"                                    \
                     "v_mov_b32 %2, %5"                                        \
                     : "=v"(P_), "=v"(T_), "=v"(E_)                            \
                     : "v"(pt_.x), "v"(pt_.y), "v"(e_));
    // consumer ring read (1 DS op) + wait/extract (<=1 newer read in flight)
    #define ISSUE_C(ca_, rel_)                                                 \
        asm volatile("ds_read_b64 %0, %1" : "=v"(rel_) : "v"(ca_));
    #define WAIT_C(rel_, rt_, E_)                                              \
        asm volatile("s_waitcnt lgkmcnt(1)\n\t"                                \
                     "v_mov_b32 %0, %2\n\t"                                    \
                     "v_mov_b32 %1, %3"                                        \
                     : "=v"(rt_), "=v"(E_) : "v"(rel_.x), "v"(rel_.y));

    if (wid == 0) {
        // ------------------------- PRODUCER (snow) -------------------------
        const float TT = p[8], CFMAX = p[9], CFR = p[10], CWH = p[11];
        const float nCFMAX_TT   = -(CFMAX * TT);
        const float nCFRCFMAX   = -(CFR * CFMAX);
        const float CFRCFMAX_TT = (CFR * CFMAX) * TT;

        float SP = 0.001f, MW = 0.001f;

        // forcing chunk-copy geometry (16B-aligned: 96 = 6*16, G*12 = 48000)
        const char* xb = (const char*)x;
        const uint32_t xstep  = (uint32_t)G * 12u;
        const uint32_t gbase  = (uint32_t)g0 * 12u;
        const uint32_t lin    = (uint32_t)lane * 16u;
        const uint32_t r0     = lin / 96u;
        const uint32_t c0     = lin % 96u;          // in {0,16,32,48,64,80}
        const uint32_t rowmax = (uint32_t)(T - 1);

        #define ISSUE_CHUNK(cs_, nb_)                                          \
        {                                                                      \
            uint32_t row_ = (uint32_t)(cs_) + r0;                              \
            uint32_t col_ = c0;                                                \
            _Pragma("unroll")                                                  \
            for (int i_ = 0; i_ < NLL; ++i_) {                                 \
                const uint32_t rg_ = row_ < rowmax ? row_ : rowmax;            \
                const uint32_t go_ = rg_ * xstep + gbase + col_;               \
                __builtin_amdgcn_global_load_lds((gv_t*)(xb + go_),            \
                    (lv_t*)&fbuf[nb_][i_ * 256], 16, 0, 0);                    \
                /* +1024B = 10 rows + 64B within the 96B-row raster */         \
                row_ += 10u + (col_ >= 32u ? 1u : 0u);                         \
                col_  = (col_ >= 32u) ? (col_ - 32u) : (col_ + 64u);           \
            }                                                                  \
        }

        ISSUE_CHUNK(0, 0)

        for (int r = 0; r <= NBLK; ++r) {
            if (r < NBLK) {
                if (r + 1 < NBLK) {
                    ISSUE_CHUNK((r + 1) * KS, (r + 1) & 1)
                    asm volatile("s_waitcnt vmcnt(3)" ::: "memory");
                } else {
                    asm volatile("s_waitcnt vmcnt(0)" ::: "memory");
                }
                const int cnt = (T - r * KS < KS) ? (T - r * KS) : KS;  // 32 or 26: even
                uint32_t fa = (uint32_t)(uintptr_t)&fbuf[r & 1][gl * 3];
                float2*  R  = &ring[r & 1][0][lane];

                v2f pt0, pt1; float e0, e1;
                ISSUE_F(fa, pt0, e0) fa += 96;       // row 0
                ISSUE_F(fa, pt1, e1) fa += 96;       // row 1

                #define PROD_STEP(PT_, E_)                                     \
                {                                                              \
                    float P, Tt, E;                                            \
                    WAIT_F(PT_, E_, P, Tt, E)                                  \
                    ISSUE_F(fa, PT_, E_) fa += 96;   /* row tt+2 (pad safe) */ \
                    const float RAIN = (Tt >= TT) ? P : 0.0f;                  \
                    const float SNOW = P - RAIN;                               \
                    const float mc = fmaxf(fmaf(CFMAX, Tt, nCFMAX_TT), 0.0f);  \
                    const float rc = fmaxf(fmaf(nCFRCFMAX, Tt, CFRCFMAX_TT), 0.0f); \
                    SP += SNOW;                                                \
                    const float melt = fminf(mc, SP);                          \
                    MW += melt;                                                \
                    SP -= melt;                                                \
                    const float refr = fminf(rc, MW);                          \
                    SP += refr;                                                \
                    MW -= refr;                                                \
                    const float cw = CWH * SP;                                 \
                    const float ts = fmaxf(MW - cw, 0.0f);                     \
                    MW = fminf(MW, cw);                                        \
                    float2 rel; rel.x = RAIN + ts; rel.y = E;                  \
                    *R = rel;                                                  \
                    R += 64;                                                   \
                }

                for (int tt = 0; tt < cnt; tt += 2) {
                    PROD_STEP(pt0, e0)
                    PROD_STEP(pt1, e1)
                }
                #undef PROD_STEP
            }
            __syncthreads();
        }
        #undef ISSUE_CHUNK
    } else {
        // --------------------- CONSUMER (soil + response) ---------------------
        const float BETA = p[0], FC = p[1], K0 = p[2], K1 = p[3], K2 = p[4],
                    LP = p[5], PERCc = p[6], UZL = p[7];
        const float invLPFC = 1.0f / (LP * FC);
        const float nBLFC   = -BETA * __builtin_amdgcn_logf(FC);  // -BETA*log2(FC)
        const float OMK0    = 1.0f - K0;
        const float K0UZL   = K0 * UZL;
        const float OMK1    = 1.0f - K1;
        const float OMK2    = 1.0f - K2;

        float SM = 0.001f, SUZ = 0.001f, SLZ = 0.001f;

        char* ob = (char*)out;
        uint32_t ooff = (uint32_t)(g * NM + m) * 4u;
        const uint32_t ostep = (uint32_t)(G * NM) * 4u;

        for (int r = 0; r <= NBLK; ++r) {
            if (r >= 1) {
                const int base = (r - 1) * KS;
                const int cnt  = (T - base < KS) ? (T - base) : KS;   // even
                uint32_t ca = (uint32_t)(uintptr_t)&ring[(r - 1) & 1][0][lane];

                v2f rel0, rel1;
                ISSUE_C(ca, rel0) ca += 512;         // row 0 (512B = 64 float2)
                ISSUE_C(ca, rel1) ca += 512;         // row 1

                #define CONS_STEP(REL_)                                        \
                {                                                              \
                    float rt, E;                                               \
                    WAIT_C(REL_, rt, E)                                        \
                    ISSUE_C(ca, REL_) ca += 512;     /* row tt+2 (pad safe) */ \
                    const float lg = __builtin_amdgcn_logf(SM);                \
                    const float bl = fminf(fmaf(BETA, lg, nBLFC), 0.0f);       \
                    const float sw = __builtin_amdgcn_exp2f(bl);               \
                    const float rg = rt * sw;                                  \
                    const float SM1 = SM + rt - rg;                            \
                    const float ex = fmaxf(SM1 - FC, 0.0f);                    \
                    const float SM2 = fminf(SM1, FC);                          \
                    const float omPe = fmaf(-E, invLPFC, 1.0f);                \
                    SM = fmaxf(fmaxf(SM2 * omPe, SM2 - E), 1e-5f);  /* max3 */ \
                    SUZ = SUZ + rg + ex;                                       \
                    const float pc = fminf(SUZ, PERCc);                        \
                    const float s2 = fmaxf(SUZ - PERCc, 0.0f);                 \
                    const float s3 = fminf(s2, fmaf(OMK0, s2, K0UZL));         \
                    const float s4 = s3 * OMK1;                                \
                    SUZ = s4;                                                  \
                    const float sl = SLZ + pc;                                 \
                    const float q2 = K2 * sl;                                  \
                    SLZ = sl * OMK2;                                           \
                    const float Q = (s2 - s4) + q2;                            \
                    *(float*)(ob + ooff) = Q;                                  \
                    ooff += ostep;                                             \
                }

                for (int tt = 0; tt < cnt; tt += 2) {
                    CONS_STEP(rel0)
                    CONS_STEP(rel1)
                }
                #undef CONS_STEP
            }
            __syncthreads();
        }
    }
    #undef ISSUE_F
    #undef WAIT_F
    #undef ISSUE_C
    #undef WAIT_C
}

extern "C" void kernel_launch(void* const* d_in, const int* in_sizes, int n_in,
                              void* d_out, int out_size, void* d_ws, size_t ws_size,
                              hipStream_t stream) {
    const float* x    = (const float*)d_in[0];   // [T, G, 3]
    const float* praw = (const float*)d_in[1];   // [1, G, 12, 8]
    float* out = (float*)d_out;                  // [T, G, 8]

    const int G = in_sizes[1] / (NPAR * NM);     // 4000
    const int T = in_sizes[0] / (3 * G);         // 730

    const int grid = G / 8;                      // 500 blocks x 2 waves = 1000 waves
    hbv_kernel<<<grid, 128, 0, stream>>>(x, praw, out, G, T);
}